// Round 6
// baseline (306.510 us; speedup 1.0000x reference)
//
#include <hip/hip_runtime.h>

#define BDIM 4
#define CDIM 256
#define HDIM 128
#define WDIM 128
#define PP   21
#define DD   10
#define HW   (HDIM*WDIM)

typedef __attribute__((ext_vector_type(8))) short short8;
typedef __attribute__((ext_vector_type(4))) float f32x4;

__device__ __forceinline__ unsigned short f2bf(float f) {
    union { float f; unsigned u; } v; v.f = f;
    unsigned u = v.u;
    return (unsigned short)((u + 0x7FFFu + ((u >> 16) & 1u)) >> 16);  // RNE
}

// ---------------- pre-pass: fp32 [b][c][p] -> bf16 [b][p][c] ----------------
__global__ __launch_bounds__(256)
void transpose_bf16_kernel(const float* __restrict__ in1,
                           const float* __restrict__ in2,
                           unsigned short* __restrict__ out1,
                           unsigned short* __restrict__ out2) {
    __shared__ float tile[64 * 64];
    const int bid = blockIdx.x;
    const float* src;
    unsigned short* dst;
    const int t4 = bid & 4095;
    if (bid >> 12) { src = in2; dst = out2; } else { src = in1; dst = out1; }
    const int b   = t4 >> 10;
    const int rem = t4 & 1023;
    const int c0  = (rem >> 8) * 64;
    const int p0  = (rem & 255) * 64;
    const int t   = threadIdx.x;

    // phase 1: coalesced fp32 read, swizzled LDS write [c][p ^ (c&28)]
    {
        const int c_l = t >> 2, pq = t & 3;
        const int swz = c_l & 28;
        const float* s = src + ((size_t)(b * CDIM + c0 + c_l)) * HW + p0 + pq * 16;
        #pragma unroll
        for (int i = 0; i < 4; ++i) {
            const float4 v = *(const float4*)(s + i * 4);
            *(float4*)&tile[c_l * 64 + ((pq * 16 + i * 4) ^ swz)] = v;
        }
    }
    __syncthreads();
    // phase 2: gather 8 consecutive channels per lane, cvt, coalesced store
    #pragma unroll
    for (int it = 0; it < 2; ++it) {
        const int idx = t + it * 256;
        const int pr  = idx >> 3;          // p within tile (0..63)
        const int cl8 = (idx & 7) * 8;     // first channel of this lane's 8
        unsigned short vals[8];
        #pragma unroll
        for (int j = 0; j < 8; ++j) {
            const int c = cl8 + j;
            vals[j] = f2bf(tile[c * 64 + (pr ^ (c & 28))]);
        }
        *(short8*)(dst + ((size_t)(b * HW + p0 + pr)) * CDIM + c0 + cl8) =
            *(short8*)vals;
    }
}

// ---------------- main: banded MFMA correlation ----------------
// LDS window holds only s in [0,128): the old [-16,0)/[128,144) halo rows were
// touched exclusively by 16-aligned tiles the zero-skip branch already skips.
// 74.5 KB total -> 2 blocks/CU (was 92.6 KB -> 1 block/CU, barrier-serialized).
#define SW 128
#define LDS_IN2_BYTES (SW * CDIM * 2)            // 65536
#define LDS_OUT_OFF   LDS_IN2_BYTES
#define LDS_TOTAL     (LDS_IN2_BYTES + PP * WDIM * 4)   // 76288

__global__ __launch_bounds__(512, 4)
void corr_mfma_kernel(const unsigned short* __restrict__ in1t,
                      const unsigned short* __restrict__ in2t,
                      float* __restrict__ out) {
    extern __shared__ char lds[];
    float* souts = (float*)(lds + LDS_OUT_OFF);  // [21][128] band bounce

    const int tid  = threadIdx.x;
    const int lane = tid & 63;
    const int w    = tid >> 6;    // wave 0..7 -> x-tile
    const int x0   = w * 16;
    const int col  = lane & 15;
    const int g    = lane >> 4;

    // XCD-bijective swizzle: 512 blocks, 8 XCDs, each XCD walks 64 consecutive (b,y)
    const int bid = blockIdx.x;
    const int logical = (bid & 7) * 64 + (bid >> 3);
    const int b = logical >> 7;
    const int y = logical & 127;

    // in1 B-fragments for this wave's x-tile, all K=256: resident across ph loop.
    // frag layout: n = lane&15 (x), k = (lane>>4)*8 + j  (consistent k-map with A)
    short8 bfr[8];
    {
        const unsigned short* p1 =
            in1t + ((size_t)((b * HDIM + y) * WDIM + x0 + col)) * CDIM + g * 8;
        #pragma unroll
        for (int k = 0; k < 8; ++k) bfr[k] = *(const short8*)(p1 + k * 32);
    }

    const int ph_start = (DD - y) > 0 ? (DD - y) : 0;          // first valid u
    const int ph_end   = (HDIM + DD - y) < PP ? (HDIM + DD - y) : PP;

    const unsigned short* in2b = in2t + (size_t)b * HW * CDIM;
    short8 sreg[8];

    auto PRELOAD = [&](int ph) {
        const int u = y + ph - DD;
        #pragma unroll
        for (int i = 0; i < 8; ++i) {
            const int idx = tid + i * 512;       // 4096 chunks: 128 rows x 32
            const int s   = idx >> 5;            // lds row = s (all in-bounds)
            const int c0  = (idx & 31) * 8;
            sreg[i] = *(const short8*)(in2b + ((size_t)(u * WDIM + s)) * CDIM + c0);
        }
    };

    PRELOAD(ph_start);

    for (int ph = 0; ph < PP; ++ph) {
        const int u = y + ph - DD;
        const bool valid = (u >= 0) && (u < HDIM);   // block-uniform
        float* outp = out + (((size_t)(b * PP + ph)) * PP) * HW + (size_t)y * WDIM;
        if (valid) {
            // write staged row into swizzled LDS [s][c], byte ^= (s&7)<<4
            #pragma unroll
            for (int i = 0; i < 8; ++i) {
                const int idx  = tid + i * 512;
                const int row  = idx >> 5;
                const int dstb = (idx * 16) ^ ((row & 7) << 4);
                *(short8*)(lds + dstb) = sreg[i];
            }
            __syncthreads();
            if (ph + 1 < ph_end) PRELOAD(ph + 1);   // hide HBM latency under MFMA

            // 3 s-tiles at s_base = x0-16+st*16 ; A: m = lane&15 (s), k = g*8+j
            #pragma unroll
            for (int st = 0; st < 3; ++st) {
                f32x4 acc = {0.f, 0.f, 0.f, 0.f};
                const int s_lo = x0 + st * 16 - 16;           // s of tile row 0
                if (s_lo >= 0 && s_lo < WDIM) {               // skip zero-halo tiles
                    const int srow = s_lo + col;              // actual s
                    const int base = srow * 512 + g * 16;
                    const int swz  = (srow & 7) << 4;
                    #pragma unroll
                    for (int k = 0; k < 8; ++k) {
                        const short8 afr = *(const short8*)(lds + ((base + k * 64) ^ swz));
                        acc = __builtin_amdgcn_mfma_f32_16x16x32_bf16(afr, bfr[k], acc, 0, 0, 0);
                    }
                }
                // band extract: D row m=g*4+r -> s, D col n=col -> x ; pw = s-x+10
                #pragma unroll
                for (int r = 0; r < 4; ++r) {
                    const int pw = st * 16 + g * 4 + r - col - 6;
                    if (pw >= 0 && pw < PP)
                        souts[pw * WDIM + x0 + col] = acc[r];
                }
            }
            __syncthreads();
            // coalesced store of [21][128] band
            #pragma unroll
            for (int it = 0; it < 2; ++it) {
                const int idx = tid + it * 512;
                if (idx < PP * 32) {
                    const int pw = idx >> 5;
                    const int x4 = (idx & 31) * 4;
                    *(float4*)(outp + (size_t)pw * HW + x4) =
                        *(const float4*)&souts[pw * WDIM + x4];
                }
            }
        } else {
            const float4 z = make_float4(0.f, 0.f, 0.f, 0.f);
            #pragma unroll
            for (int it = 0; it < 2; ++it) {
                const int idx = tid + it * 512;
                if (idx < PP * 32) {
                    const int pw = idx >> 5;
                    const int x4 = (idx & 31) * 4;
                    *(float4*)(outp + (size_t)pw * HW + x4) = z;
                }
            }
        }
    }
}

// ---------------- fallback (round-0 fp32 kernel, known-correct) ----------------
#define KC   8
#define NSLOT 8
#define S2W  152

__global__ __launch_bounds__(256, 2)
void corr_kernel(const float* __restrict__ in1,
                 const float* __restrict__ in2,
                 float* __restrict__ out) {
    __shared__ float s1[KC][WDIM];
    __shared__ float s2[NSLOT][KC][S2W];
    const int tid  = threadIdx.x;
    const int xg   = tid & 31;
    const int slot = tid >> 5;
    const int bid  = blockIdx.x;
    const int b    = bid >> 7;
    const int y    = bid & 127;
    const float* in1row = in1 + (((size_t)b * CDIM) * HDIM + y) * WDIM;
    for (int pass = 0; pass < 3; ++pass) {
        const int ph = slot + NSLOT * pass;
        float acc[PP][4];
        #pragma unroll
        for (int pw = 0; pw < PP; ++pw)
            #pragma unroll
            for (int px = 0; px < 4; ++px) acc[pw][px] = 0.0f;
        for (int c0 = 0; c0 < CDIM; c0 += KC) {
            __syncthreads();
            {
                const int c = tid >> 5;
                const int x = (tid & 31) * 4;
                const float4 v = *(const float4*)(in1row + (size_t)(c0 + c) * HW + x);
                *(float4*)&s1[c][x] = v;
            }
            #pragma unroll
            for (int i = 0; i < 10; ++i) {
                const int idx = tid + 256 * i;
                if (idx < NSLOT * KC * 38) {
                    const int col4 = idx % 38;
                    const int rc   = idx / 38;
                    const int c    = rc & (KC - 1);
                    const int s    = rc >> 3;
                    const int uu   = y + s + NSLOT * pass - DD;
                    const int x0   = col4 * 4 - 12;
                    float4 v = make_float4(0.f, 0.f, 0.f, 0.f);
                    if (uu >= 0 && uu < HDIM && x0 >= 0 && x0 + 3 < WDIM)
                        v = *(const float4*)(in2 + (((size_t)(b * CDIM + c0 + c)) * HDIM + uu) * WDIM + x0);
                    *(float4*)&s2[s][c][col4 * 4] = v;
                }
            }
            __syncthreads();
            if (ph < PP) {
                #pragma unroll
                for (int c = 0; c < KC; ++c) {
                    float a[4];
                    *(float4*)a = *(const float4*)&s1[c][xg * 4];
                    float wv[28];
                    #pragma unroll
                    for (int j = 0; j < 7; ++j)
                        *(float4*)&wv[4 * j] = *(const float4*)&s2[slot][c][xg * 4 + 4 * j];
                    #pragma unroll
                    for (int pw = 0; pw < PP; ++pw)
                        #pragma unroll
                        for (int px = 0; px < 4; ++px)
                            acc[pw][px] = fmaf(a[px], wv[px + pw + 2], acc[pw][px]);
                }
            }
        }
        if (ph < PP) {
            #pragma unroll
            for (int pw = 0; pw < PP; ++pw) {
                const size_t o = ((((size_t)b * PP + ph) * PP + pw) * HDIM + y) * WDIM + xg * 4;
                float4 v;
                v.x = acc[pw][0]; v.y = acc[pw][1]; v.z = acc[pw][2]; v.w = acc[pw][3];
                *(float4*)(out + o) = v;
            }
        }
    }
}

extern "C" void kernel_launch(void* const* d_in, const int* in_sizes, int n_in,
                              void* d_out, int out_size, void* d_ws, size_t ws_size,
                              hipStream_t stream) {
    const float* in1 = (const float*)d_in[0];
    const float* in2 = (const float*)d_in[1];
    float* out = (float*)d_out;

    const size_t elems = (size_t)BDIM * HW * CDIM;           // per input
    const size_t need  = 2 * elems * sizeof(unsigned short); // 64 MB
    if (ws_size >= need) {
        unsigned short* t1 = (unsigned short*)d_ws;
        unsigned short* t2 = t1 + elems;
        transpose_bf16_kernel<<<2 * BDIM * 4 * 256, 256, 0, stream>>>(in1, in2, t1, t2);
        hipFuncSetAttribute((const void*)corr_mfma_kernel,
                            hipFuncAttributeMaxDynamicSharedMemorySize, LDS_TOTAL);
        corr_mfma_kernel<<<BDIM * HDIM, 512, LDS_TOTAL, stream>>>(t1, t2, out);
    } else {
        corr_kernel<<<BDIM * HDIM, 256, 0, stream>>>(in1, in2, out);
    }
}

// Round 9
// 302.419 us; speedup vs baseline: 1.0135x; 1.0135x over previous
//
#include <hip/hip_runtime.h>

#define BDIM 4
#define CDIM 256
#define HDIM 128
#define WDIM 128
#define PP   21
#define DD   10
#define HW   (HDIM*WDIM)

typedef __attribute__((ext_vector_type(8))) short short8;
typedef __attribute__((ext_vector_type(4))) float f32x4;

__device__ __forceinline__ unsigned short f2bf(float f) {
    union { float f; unsigned u; } v; v.f = f;
    unsigned u = v.u;
    return (unsigned short)((u + 0x7FFFu + ((u >> 16) & 1u)) >> 16);  // RNE
}

// ---------------- pre-pass: fp32 [b][c][p] -> bf16 [b][p][c] ----------------
__global__ __launch_bounds__(256)
void transpose_bf16_kernel(const float* __restrict__ in1,
                           const float* __restrict__ in2,
                           unsigned short* __restrict__ out1,
                           unsigned short* __restrict__ out2) {
    __shared__ float tile[64 * 64];
    const int bid = blockIdx.x;
    const float* src;
    unsigned short* dst;
    const int t4 = bid & 4095;
    if (bid >> 12) { src = in2; dst = out2; } else { src = in1; dst = out1; }
    const int b   = t4 >> 10;
    const int rem = t4 & 1023;
    const int c0  = (rem >> 8) * 64;
    const int p0  = (rem & 255) * 64;
    const int t   = threadIdx.x;

    // phase 1: coalesced fp32 read, swizzled LDS write [c][p ^ (c&28)]
    {
        const int c_l = t >> 2, pq = t & 3;
        const int swz = c_l & 28;
        const float* s = src + ((size_t)(b * CDIM + c0 + c_l)) * HW + p0 + pq * 16;
        #pragma unroll
        for (int i = 0; i < 4; ++i) {
            const float4 v = *(const float4*)(s + i * 4);
            *(float4*)&tile[c_l * 64 + ((pq * 16 + i * 4) ^ swz)] = v;
        }
    }
    __syncthreads();
    // phase 2: gather 8 consecutive channels per lane, cvt, coalesced store
    #pragma unroll
    for (int it = 0; it < 2; ++it) {
        const int idx = t + it * 256;
        const int pr  = idx >> 3;          // p within tile (0..63)
        const int cl8 = (idx & 7) * 8;     // first channel of this lane's 8
        unsigned short vals[8];
        #pragma unroll
        for (int j = 0; j < 8; ++j) {
            const int c = cl8 + j;
            vals[j] = f2bf(tile[c * 64 + (pr ^ (c & 28))]);
        }
        *(short8*)(dst + ((size_t)(b * HW + p0 + pr)) * CDIM + c0 + cl8) =
            *(short8*)vals;
    }
}

// ---------------- main: banded MFMA correlation ----------------
// 2-wave (128-thr) blocks, one per (b, y, 32-x strip). Each block stages its
// own 64-row s-window (32 KB) -> 4 independent blocks/CU (static 35 KB LDS):
// barriers rendezvous only 2 waves, and 4 blocks pipeline across each other.
// Grid = 2048 = 2x residency -> rolling ~32-y L2 window per XCD (round-5's
// accidental locality, now by design; round-6's full-residency thrashed L2).
#define SP 36   // souts row pitch (floats): banks spread, 144B keeps f4 align

__global__ __launch_bounds__(128, 2)
void corr_mfma_kernel(const unsigned short* __restrict__ in1t,
                      const unsigned short* __restrict__ in2t,
                      float* __restrict__ out) {
    __shared__ __align__(16) char lds[64 * 512];   // 64 s-rows x 256c x 2B
    __shared__ __align__(16) float souts[PP * SP]; // band bounce, pitch 36

    const int tid  = threadIdx.x;
    const int lane = tid & 63;
    const int w    = tid >> 6;    // wave 0..1 -> x-16-subtile
    const int col  = lane & 15;
    const int g    = lane >> 4;

    // XCD swizzle: 2048 blocks, 8 XCDs, each XCD walks 256 consecutive logical
    const int bid = blockIdx.x;
    const int logical = (bid & 7) * 256 + (bid >> 3);
    const int xg = logical & 3;          // 32-x strip
    const int yb = logical >> 2;
    const int b  = yb >> 7;
    const int y  = yb & 127;
    const int x0 = xg * 32;

    // in1 B-fragments for wave's 16-x subtile, K=256 resident across ph loop
    short8 bfr[8];
    {
        const unsigned short* p1 =
            in1t + ((size_t)((b * HDIM + y) * WDIM + x0 + w * 16 + col)) * CDIM + g * 8;
        #pragma unroll
        for (int k = 0; k < 8; ++k) bfr[k] = *(const short8*)(p1 + k * 32);
    }

    const int ph_start = (DD - y) > 0 ? (DD - y) : 0;
    const int ph_end   = (HDIM + DD - y) < PP ? (HDIM + DD - y) : PP;

    const unsigned short* in2b = in2t + (size_t)b * HW * CDIM;
    short8 sreg[16];

    auto PRELOAD = [&](int ph) {
        const int u = y + ph - DD;
        #pragma unroll
        for (int i = 0; i < 16; ++i) {
            const int idx = tid + i * 128;     // 2048 16B chunks = 64 rows
            const int row = idx >> 5;
            const int s   = x0 - 16 + row;     // global s of this LDS row
            const int c0  = (idx & 31) * 8;
            short8 v = {0, 0, 0, 0, 0, 0, 0, 0};
            if (s >= 0 && s < WDIM)
                v = *(const short8*)(in2b + ((size_t)(u * WDIM + s)) * CDIM + c0);
            sreg[i] = v;
        }
    };

    PRELOAD(ph_start);

    for (int ph = 0; ph < PP; ++ph) {
        const int u = y + ph - DD;
        const bool valid = (u >= 0) && (u < HDIM);   // block-uniform
        float* outp = out + (((size_t)(b * PP + ph)) * PP) * HW
                          + (size_t)y * WDIM + x0;
        if (valid) {
            // stage row into swizzled LDS [row][c], byte ^= (row&7)<<4
            #pragma unroll
            for (int i = 0; i < 16; ++i) {
                const int idx  = tid + i * 128;
                const int row  = idx >> 5;
                const int dstb = (idx * 16) ^ ((row & 7) << 4);
                *(short8*)(lds + dstb) = sreg[i];
            }
            __syncthreads();
            if (ph + 1 < ph_end) PRELOAD(ph + 1);   // hide HBM under MFMA

            // 3 s-tiles; local row base (w+st)*16, global s_lo = x0+(w+st-1)*16
            #pragma unroll
            for (int st = 0; st < 3; ++st) {
                f32x4 acc = {0.f, 0.f, 0.f, 0.f};
                const int s_lo = x0 + (w + st) * 16 - 16;
                if (s_lo >= 0 && s_lo < WDIM) {       // skip zero-halo tiles
                    const int srow = (w + st) * 16 + col;   // local LDS row
                    const int base = srow * 512 + g * 16;
                    const int swz  = (srow & 7) << 4;
                    #pragma unroll
                    for (int k = 0; k < 8; ++k) {
                        const short8 afr = *(const short8*)(lds + ((base + k * 64) ^ swz));
                        acc = __builtin_amdgcn_mfma_f32_16x16x32_bf16(afr, bfr[k], acc, 0, 0, 0);
                    }
                }
                // band extract: D row m=g*4+r -> s, col n -> x ; pw = s-x+10
                #pragma unroll
                for (int r = 0; r < 4; ++r) {
                    const int pw = st * 16 + g * 4 + r - col - 6;
                    if (pw >= 0 && pw < PP)
                        souts[pw * SP + w * 16 + col] = acc[r];
                }
            }
            __syncthreads();
            // coalesced store of [21][32] band strip
            #pragma unroll
            for (int it = 0; it < 2; ++it) {
                const int idx = tid + it * 128;
                if (idx < PP * 8) {
                    const int pw = idx >> 3;
                    const int x4 = (idx & 7) * 4;
                    *(float4*)(outp + (size_t)pw * HW + x4) =
                        *(const float4*)&souts[pw * SP + x4];
                }
            }
        } else {
            const float4 z = make_float4(0.f, 0.f, 0.f, 0.f);
            #pragma unroll
            for (int it = 0; it < 2; ++it) {
                const int idx = tid + it * 128;
                if (idx < PP * 8) {
                    const int pw = idx >> 3;
                    const int x4 = (idx & 7) * 4;
                    *(float4*)(outp + (size_t)pw * HW + x4) = z;
                }
            }
        }
    }
}

// ---------------- fallback (round-0 fp32 kernel, known-correct) ----------------
#define KC   8
#define NSLOT 8
#define S2W  152

__global__ __launch_bounds__(256, 2)
void corr_kernel(const float* __restrict__ in1,
                 const float* __restrict__ in2,
                 float* __restrict__ out) {
    __shared__ float s1[KC][WDIM];
    __shared__ float s2[NSLOT][KC][S2W];
    const int tid  = threadIdx.x;
    const int xg   = tid & 31;
    const int slot = tid >> 5;
    const int bid  = blockIdx.x;
    const int b    = bid >> 7;
    const int y    = bid & 127;
    const float* in1row = in1 + (((size_t)b * CDIM) * HDIM + y) * WDIM;
    for (int pass = 0; pass < 3; ++pass) {
        const int ph = slot + NSLOT * pass;
        float acc[PP][4];
        #pragma unroll
        for (int pw = 0; pw < PP; ++pw)
            #pragma unroll
            for (int px = 0; px < 4; ++px) acc[pw][px] = 0.0f;
        for (int c0 = 0; c0 < CDIM; c0 += KC) {
            __syncthreads();
            {
                const int c = tid >> 5;
                const int x = (tid & 31) * 4;
                const float4 v = *(const float4*)(in1row + (size_t)(c0 + c) * HW + x);
                *(float4*)&s1[c][x] = v;
            }
            #pragma unroll
            for (int i = 0; i < 10; ++i) {
                const int idx = tid + 256 * i;
                if (idx < NSLOT * KC * 38) {
                    const int col4 = idx % 38;
                    const int rc   = idx / 38;
                    const int c    = rc & (KC - 1);
                    const int s    = rc >> 3;
                    const int uu   = y + s + NSLOT * pass - DD;
                    const int x0   = col4 * 4 - 12;
                    float4 v = make_float4(0.f, 0.f, 0.f, 0.f);
                    if (uu >= 0 && uu < HDIM && x0 >= 0 && x0 + 3 < WDIM)
                        v = *(const float4*)(in2 + (((size_t)(b * CDIM + c0 + c)) * HDIM + uu) * WDIM + x0);
                    *(float4*)&s2[s][c][col4 * 4] = v;
                }
            }
            __syncthreads();
            if (ph < PP) {
                #pragma unroll
                for (int c = 0; c < KC; ++c) {
                    float a[4];
                    *(float4*)a = *(const float4*)&s1[c][xg * 4];
                    float wv[28];
                    #pragma unroll
                    for (int j = 0; j < 7; ++j)
                        *(float4*)&wv[4 * j] = *(const float4*)&s2[slot][c][xg * 4 + 4 * j];
                    #pragma unroll
                    for (int pw = 0; pw < PP; ++pw)
                        #pragma unroll
                        for (int px = 0; px < 4; ++px)
                            acc[pw][px] = fmaf(a[px], wv[px + pw + 2], acc[pw][px]);
                }
            }
        }
        if (ph < PP) {
            #pragma unroll
            for (int pw = 0; pw < PP; ++pw) {
                const size_t o = ((((size_t)b * PP + ph) * PP + pw) * HDIM + y) * WDIM + xg * 4;
                float4 v;
                v.x = acc[pw][0]; v.y = acc[pw][1]; v.z = acc[pw][2]; v.w = acc[pw][3];
                *(float4*)(out + o) = v;
            }
        }
    }
}

extern "C" void kernel_launch(void* const* d_in, const int* in_sizes, int n_in,
                              void* d_out, int out_size, void* d_ws, size_t ws_size,
                              hipStream_t stream) {
    const float* in1 = (const float*)d_in[0];
    const float* in2 = (const float*)d_in[1];
    float* out = (float*)d_out;

    const size_t elems = (size_t)BDIM * HW * CDIM;           // per input
    const size_t need  = 2 * elems * sizeof(unsigned short); // 64 MB
    if (ws_size >= need) {
        unsigned short* t1 = (unsigned short*)d_ws;
        unsigned short* t2 = t1 + elems;
        transpose_bf16_kernel<<<2 * BDIM * 4 * 256, 256, 0, stream>>>(in1, in2, t1, t2);
        corr_mfma_kernel<<<BDIM * HDIM * 4, 128, 0, stream>>>(t1, t2, out);
    } else {
        corr_kernel<<<BDIM * HDIM, 256, 0, stream>>>(in1, in2, out);
    }
}